// Round 13
// baseline (381.068 us; speedup 1.0000x reference)
//
#include <hip/hip_runtime.h>

#define N_CODES 512
#define D 32
#define NVEC (8192 * 64)          // 524288 vectors
#define ZQ_ELEMS (NVEC * D)
#define NBLK (NVEC / 256)         // 2048 main blocks
#define MARGIN_TRIG 7e-5f
#define SA (-1.0f / 16.0f)        // A = SA*z   (power of 2, exact)
#define SB (32.0f)                // B = SB*w   -> A*B sums to -2 z.w
#define KMASK 0xFFFFFFE0u         // clear 5 low mantissa bits for t-index
#define FLAG_OFS 1024             // idx += 1024 marks "needs exact rescan"

typedef _Float16 half8 __attribute__((ext_vector_type(8)));
typedef float f32x4 __attribute__((ext_vector_type(4)));

// ws: @0 double partials[2048] only
__device__ __forceinline__ unsigned umin_(unsigned a, unsigned b) { return a < b ? a : b; }
__device__ __forceinline__ unsigned umax_(unsigned a, unsigned b) { return a > b ? a : b; }

// wave owns 128 codes (8 B-fragments built in-register from cb); 16 row-tiles.
__global__ __launch_bounds__(256, 8) void vq_main(
        const float* __restrict__ z, const float* __restrict__ cbf,
        float* __restrict__ zq, float* __restrict__ idxo,
        double* __restrict__ partials) {
    __shared__ __align__(16) float4 pw[256][4];   // per-row per-wave (m1,m2,ai,-)
    __shared__ float zz_s[256];
    __shared__ int win_s[256];
    __shared__ double wsum[4];
    const int tid = threadIdx.x;
    const int l = tid & 63, wv = tid >> 6;
    const int g16 = l & 15, kg = l >> 4, koff = kg * 8;
    const int vblock = blockIdx.x * 256;          // block owns 256 rows
    const unsigned long long grpmask = 0xFFFFull << (kg * 16);

    // build this wave's 8 B-fragments + C-init from cb (L2-hot, once per wave)
    half8 Breg[8];
    float cin[8];
#pragma unroll
    for (int j = 0; j < 8; ++j) {
        int code = (wv * 8 + j) * 16 + g16;
        const float4* wp = (const float4*)(cbf + (size_t)code * D + koff);
        float4 w0 = wp[0], w1 = wp[1];
        half8 h;
        h[0] = (_Float16)(w0.x * SB); h[1] = (_Float16)(w0.y * SB);
        h[2] = (_Float16)(w0.z * SB); h[3] = (_Float16)(w0.w * SB);
        h[4] = (_Float16)(w1.x * SB); h[5] = (_Float16)(w1.y * SB);
        h[6] = (_Float16)(w1.z * SB); h[7] = (_Float16)(w1.w * SB);
        Breg[j] = h;
        float s = 0.f;
        s = fmaf(w0.x, w0.x, s); s = fmaf(w0.y, w0.y, s);
        s = fmaf(w0.z, w0.z, s); s = fmaf(w0.w, w0.w, s);
        s = fmaf(w1.x, w1.x, s); s = fmaf(w1.y, w1.y, s);
        s = fmaf(w1.z, w1.z, s); s = fmaf(w1.w, w1.w, s);
        s += __shfl_xor(s, 16, 64);               // sum the 4 k-chunks
        s += __shfl_xor(s, 32, 64);
        cin[j] = 1.0f + s;                        // +1 => scores positive
    }

#pragma unroll 1
    for (int tt = 0; tt < 16; ++tt) {
        const float* zp = z + (size_t)(vblock + tt * 16 + g16) * D + koff;
        float4 a0 = *(const float4*)zp;
        float4 a1 = *(const float4*)(zp + 4);
        half8 A;
        A[0] = (_Float16)(a0.x * SA); A[1] = (_Float16)(a0.y * SA);
        A[2] = (_Float16)(a0.z * SA); A[3] = (_Float16)(a0.w * SA);
        A[4] = (_Float16)(a1.x * SA); A[5] = (_Float16)(a1.y * SA);
        A[6] = (_Float16)(a1.z * SA); A[7] = (_Float16)(a1.w * SA);
        if (wv == 0) {                            // ||z||^2 (wave 0 only)
            float ss = 0.f;
            ss = fmaf(a0.x, a0.x, ss); ss = fmaf(a0.y, a0.y, ss);
            ss = fmaf(a0.z, a0.z, ss); ss = fmaf(a0.w, a0.w, ss);
            ss = fmaf(a1.x, a1.x, ss); ss = fmaf(a1.y, a1.y, ss);
            ss = fmaf(a1.z, a1.z, ss); ss = fmaf(a1.w, a1.w, ss);
            ss += __shfl_xor(ss, 16, 64);
            ss += __shfl_xor(ss, 32, 64);
            if (kg == 0) zz_s[tt * 16 + l] = ss;
        }

        unsigned m1u[4], m2u[4];
#pragma unroll
        for (int r = 0; r < 4; ++r) { m1u[r] = 0xFFFFFFFFu; m2u[r] = 0xFFFFFFFFu; }

#pragma unroll
        for (int p = 0; p < 4; ++p) {
            f32x4 acc0, acc1;
            float c0 = cin[2 * p], c1 = cin[2 * p + 1];
            acc0[0] = c0; acc0[1] = c0; acc0[2] = c0; acc0[3] = c0;
            acc0 = __builtin_amdgcn_mfma_f32_16x16x32_f16(A, Breg[2 * p], acc0, 0, 0, 0);
            acc1[0] = c1; acc1[1] = c1; acc1[2] = c1; acc1[3] = c1;
            acc1 = __builtin_amdgcn_mfma_f32_16x16x32_f16(A, Breg[2 * p + 1], acc1, 0, 0, 0);
            unsigned t0 = (unsigned)(wv * 8 + 2 * p), t1 = t0 + 1;
#pragma unroll
            for (int r = 0; r < 4; ++r) {
                unsigned k0 = (__float_as_uint(acc0[r]) & KMASK) | t0;
                unsigned k1 = (__float_as_uint(acc1[r]) & KMASK) | t1;
                unsigned med;
                asm("v_med3_u32 %0, %1, %2, %3"
                    : "=v"(med) : "v"(m1u[r]), "v"(k0), "v"(k1));
                asm("v_min3_u32 %0, %1, %2, %3"
                    : "=v"(m1u[r]) : "v"(m1u[r]), "v"(k0), "v"(k1));
                m2u[r] = umin_(m2u[r], med);
            }
        }

        // joint (min, 2nd-min) butterfly in packed-uint domain; idx via ballot
#pragma unroll
        for (int r = 0; r < 4; ++r) {
            unsigned b1 = m1u[r], b2 = m2u[r];
#pragma unroll
            for (int dd = 1; dd <= 8; dd <<= 1) {
                unsigned o1 = __shfl_xor(b1, dd, 64);
                unsigned o2 = __shfl_xor(b2, dd, 64);
                b2 = umin_(umin_(b2, o2), umax_(b1, o1));
                b1 = umin_(b1, o1);
            }
            unsigned long long bal = __ballot(m1u[r] == b1) & grpmask;
            int wg16 = __builtin_ctzll(bal) - kg * 16;   // first-index tie-break
            int ai = (int)(b1 & 31u) * 16 + wg16;
            if (g16 == r)   // holder writes row tt*16 + 4*kg + r, slot wv
                pw[tt * 16 + 4 * kg + r][wv] =
                    make_float4(__uint_as_float(b1 & KMASK),
                                __uint_as_float(b2 & KMASK),
                                __int_as_float(ai), 0.f);
        }
    }
    __syncthreads();

    // ---- epilogue: merge 4 wave-partials per row (thread tid = row) ----
    float b1 = 1e30f, b2 = 1e30f; int bai = 0x7FFFFFFF;
#pragma unroll
    for (int w = 0; w < 4; ++w) {
        float4 p = pw[tid][w];
        float v1 = p.x, v2 = p.y; int ai = __float_as_int(p.z);
        float nb2 = fminf(fmaxf(b1, v1), fminf(b2, v2));
        bool take = (v1 < b1) || (v1 == b1 && ai < bai);
        bai = take ? ai : bai;
        b1 = fminf(b1, v1);
        b2 = nb2;
    }

    // loss: ||z-q||^2 = ||z||^2 + (m1 - 1)
    {
        double contrib = ((double)b1 - 1.0) + (double)zz_s[tid];
#pragma unroll
        for (int off = 32; off; off >>= 1) contrib += __shfl_down(contrib, off, 64);
        if (l == 0) wsum[wv] = contrib;
    }

    // idx (+1024 marks near-tie rows for the fixup pass); no atomics anywhere
    bool flag = (b2 - b1) <= MARGIN_TRIG;
    idxo[vblock + tid] = (float)(bai + (flag ? FLAG_OFS : 0));
    win_s[tid] = bai;
    __syncthreads();
    if (tid == 0) partials[blockIdx.x] = wsum[0] + wsum[1] + wsum[2] + wsum[3];

    // z_q: 256 threads x 8 iters cover 256 rows x 32 floats, fully contiguous
    {
        const float4* cb4 = (const float4*)cbf;
        float4* zq4 = (float4*)zq;
        const int c = tid & 7;
#pragma unroll
        for (int it = 0; it < 8; ++it) {
            int r = it * 32 + (tid >> 3);
            int win = win_s[r];
            float4 val = cb4[(size_t)win * 8 + c];
            zq4[(size_t)(vblock + r) * 8 + c] = val;
        }
    }
}

// cold path: scan idxo for flagged rows (>=1024), exact wave-parallel rescan
// (f64 z.w AND w.w per candidate -> platonic f32 terms, reference association).
// Block 0 also does the final loss reduction.
__global__ __launch_bounds__(256, 2) void vq_fixup(
        const float* __restrict__ z, const float* __restrict__ cbf,
        float* __restrict__ zq, float* __restrict__ idxo,
        const double* __restrict__ partials, float* __restrict__ loss_out) {
    if (blockIdx.x == 0) {                      // final loss reduction
        const int tid = threadIdx.x;
        double s = 0.0;
#pragma unroll
        for (int i = 0; i < NBLK / 256; ++i) s += partials[i * 256 + tid];
#pragma unroll
        for (int off = 32; off; off >>= 1) s += __shfl_down(s, off, 64);
        __shared__ double w4[4];
        if ((tid & 63) == 0) w4[tid >> 6] = s;
        __syncthreads();
        if (tid == 0)
            *loss_out = (float)(1.25 * (w4[0] + w4[1] + w4[2] + w4[3])
                                / (double)ZQ_ELEMS);
    }

    const int l = threadIdx.x & 63;
    const int wave = (blockIdx.x * blockDim.x + threadIdx.x) >> 6;
    const int nwaves = (gridDim.x * blockDim.x) >> 6;

    for (int ch = wave; ch < NVEC / 64; ch += nwaves) {
        int v0 = ch * 64;
        float fv = idxo[v0 + l];
        unsigned long long m = __ballot(fv >= (float)FLAG_OFS);
        while (m) {
            int b = __builtin_ctzll(m); m &= m - 1;
            int v = v0 + b;
            const float* zv = z + (size_t)v * D;    // uniform addr -> broadcast
            float4 zr[8];                           // hoist z once (32 regs)
#pragma unroll
            for (int q = 0; q < 8; ++q) zr[q] = *(const float4*)(zv + q * 4);
            double Ad = 0.0;
#pragma unroll
            for (int q = 0; q < 8; ++q) {
                Ad = fma((double)zr[q].x, (double)zr[q].x, Ad);
                Ad = fma((double)zr[q].y, (double)zr[q].y, Ad);
                Ad = fma((double)zr[q].z, (double)zr[q].z, Ad);
                Ad = fma((double)zr[q].w, (double)zr[q].w, Ad);
            }
            float Af = (float)Ad;
            float best = 1e30f; int bi = 0;
#pragma unroll 2
            for (int j = 0; j < 8; ++j) {
                int c = l * 8 + j;                  // lane-major => index-ordered
                const float* w = cbf + (size_t)c * D;
                double bd = 0.0, cw = 0.0;
#pragma unroll
                for (int q = 0; q < 8; ++q) {
                    float4 wq = *(const float4*)(w + q * 4);
                    bd = fma((double)zr[q].x, (double)wq.x, bd);
                    bd = fma((double)zr[q].y, (double)wq.y, bd);
                    bd = fma((double)zr[q].z, (double)wq.z, bd);
                    bd = fma((double)zr[q].w, (double)wq.w, bd);
                    cw = fma((double)wq.x, (double)wq.x, cw);
                    cw = fma((double)wq.y, (double)wq.y, cw);
                    cw = fma((double)wq.z, (double)wq.z, cw);
                    cw = fma((double)wq.w, (double)wq.w, cw);
                }
                float B32 = (float)bd;              // platonic dot
                float C32 = (float)cw;              // platonic ||w||^2
                float dq = __fadd_rn(__fsub_rn(Af, __fmul_rn(2.0f, B32)), C32);
                if (dq < best) { best = dq; bi = c; }
            }
#pragma unroll
            for (int dd = 1; dd < 64; dd <<= 1) {
                float ob = __shfl_xor(best, dd, 64);
                int obi = __shfl_xor(bi, dd, 64);
                bool take = (ob < best) || (ob == best && obi < bi);
                best = take ? ob : best; bi = take ? obi : bi;
            }
            if (l == 0) idxo[v] = (float)bi;        // clears the +1024 flag too
            if (l < 8) {                            // one full 128B line
                float4 val = ((const float4*)cbf)[(size_t)bi * 8 + l];
                ((float4*)zq)[(size_t)v * 8 + l] = val;
            }
        }
    }
}

extern "C" void kernel_launch(void* const* d_in, const int* in_sizes, int n_in,
                              void* d_out, int out_size, void* d_ws, size_t ws_size,
                              hipStream_t stream) {
    const float* z  = (const float*)d_in[0];
    const float* cb = (const float*)d_in[1];
    float* out  = (float*)d_out;
    float* zq   = out;
    float* idxo = out + ZQ_ELEMS;
    float* loss = out + ZQ_ELEMS + NVEC;
    double* partials = (double*)d_ws;

    vq_main<<<NBLK, 256, 0, stream>>>(z, cb, zq, idxo, partials);
    vq_fixup<<<2048, 256, 0, stream>>>(z, cb, zq, idxo, partials, loss);
}

// Round 14
// 364.930 us; speedup vs baseline: 1.0442x; 1.0442x over previous
//
#include <hip/hip_runtime.h>

#define N_CODES 512
#define D 32
#define NVEC (8192 * 64)          // 524288 vectors
#define ZQ_ELEMS (NVEC * D)
#define NBLK (NVEC / 256)         // 2048 main blocks
#define MARGIN_TRIG 7e-5f
#define SA (-1.0f / 16.0f)        // A = SA*z   (power of 2, exact)
#define SB (32.0f)                // B = SB*w   -> A*B sums to -2 z.w
#define KMASK 0xFFFFFFE0u         // clear 5 low mantissa bits for t-index
#define FLAG_OFS 1024             // idx += 1024 marks "needs exact rescan"

typedef _Float16 half8 __attribute__((ext_vector_type(8)));
typedef float f32x4 __attribute__((ext_vector_type(4)));

// ws: @64 float ww[512] | @2112 float ww1[512] | @4160 bfrag (32768)
//     | @36928 double partials[2048]
#define WW1_OFF 2112
#define BFRAG_OFF 4160
#define PART_OFF 36928

__device__ __forceinline__ unsigned umin_(unsigned a, unsigned b) { return a < b ? a : b; }
__device__ __forceinline__ unsigned umax_(unsigned a, unsigned b) { return a > b ? a : b; }

__global__ void vq_prep(const float* __restrict__ cb, float* __restrict__ ww,
                        float* __restrict__ ww1, half8* __restrict__ bfrag) {
    int gid = blockIdx.x * 256 + threadIdx.x;   // 8 x 256 = 2048
    if (gid >= 2048) return;
    int t = gid >> 6, l = gid & 63;
    int code = t * 16 + (l & 15), koff = (l >> 4) * 8;
    const float* w = cb + (size_t)code * D + koff;
    half8 h;
#pragma unroll
    for (int j = 0; j < 8; ++j) h[j] = (_Float16)(SB * w[j]);
    bfrag[t * 64 + l] = h;                      // MFMA B-fragment lane order
    if (koff == 0) {                            // platonic ||w||^2 -> f32
        const float* wr = cb + (size_t)code * D;
        double s = 0.0;
#pragma unroll
        for (int d = 0; d < D; ++d) s = fma((double)wr[d], (double)wr[d], s);
        ww[code] = (float)s;                    // exact, for fixup formula
        ww1[code] = (float)(1.0 + s);           // C-init (+1 => scores positive)
    }
}

// wave owns 128 codes (8 B-fragments, register-resident); loops 16 row-tiles.
// (256,7): VGPR cap 73 >= measured 48 (no spill), occupancy ceiling 87%
// (R13 lesson: (256,8) cap 64 < Breg footprint -> full Breg spill, 816MB FETCH).
__global__ __launch_bounds__(256, 7) void vq_main(
        const float* __restrict__ z, const float* __restrict__ cbf,
        const half8* __restrict__ bfrag_g, const float* __restrict__ ww1_g,
        float* __restrict__ zq, float* __restrict__ idxo,
        double* __restrict__ partials) {
    __shared__ __align__(16) float4 pw[256][4];   // per-row per-wave (m1,m2,ai,-)
    __shared__ float zz_s[256];
    __shared__ int win_s[256];
    __shared__ double wsum[4];
    const int tid = threadIdx.x;
    const int l = tid & 63, wv = tid >> 6;
    const int g16 = l & 15, kg = l >> 4, koff = kg * 8;
    const int vblock = blockIdx.x * 256;          // block owns 256 rows
    const unsigned long long grpmask = 0xFFFFull << (kg * 16);

    // this wave's 8 code-tiles: t = wv*8 + j  (B + C-init held in registers)
    half8 Breg[8];
    float cin[8];
#pragma unroll
    for (int j = 0; j < 8; ++j) {
        Breg[j] = bfrag_g[(size_t)(wv * 8 + j) * 64 + l];
        cin[j] = ww1_g[(wv * 8 + j) * 16 + g16];
    }

#pragma unroll 1
    for (int tt = 0; tt < 16; ++tt) {
        const float* zp = z + (size_t)(vblock + tt * 16 + g16) * D + koff;
        float4 a0 = *(const float4*)zp;
        float4 a1 = *(const float4*)(zp + 4);
        half8 A;
        A[0] = (_Float16)(a0.x * SA); A[1] = (_Float16)(a0.y * SA);
        A[2] = (_Float16)(a0.z * SA); A[3] = (_Float16)(a0.w * SA);
        A[4] = (_Float16)(a1.x * SA); A[5] = (_Float16)(a1.y * SA);
        A[6] = (_Float16)(a1.z * SA); A[7] = (_Float16)(a1.w * SA);
        if (wv == 0) {                            // ||z||^2 (wave 0 only)
            float ss = 0.f;
            ss = fmaf(a0.x, a0.x, ss); ss = fmaf(a0.y, a0.y, ss);
            ss = fmaf(a0.z, a0.z, ss); ss = fmaf(a0.w, a0.w, ss);
            ss = fmaf(a1.x, a1.x, ss); ss = fmaf(a1.y, a1.y, ss);
            ss = fmaf(a1.z, a1.z, ss); ss = fmaf(a1.w, a1.w, ss);
            ss += __shfl_xor(ss, 16, 64);
            ss += __shfl_xor(ss, 32, 64);
            if (kg == 0) zz_s[tt * 16 + l] = ss;
        }

        unsigned m1u[4], m2u[4];
#pragma unroll
        for (int r = 0; r < 4; ++r) { m1u[r] = 0xFFFFFFFFu; m2u[r] = 0xFFFFFFFFu; }

#pragma unroll
        for (int p = 0; p < 4; ++p) {
            f32x4 acc0, acc1;
            float c0 = cin[2 * p], c1 = cin[2 * p + 1];
            acc0[0] = c0; acc0[1] = c0; acc0[2] = c0; acc0[3] = c0;
            acc0 = __builtin_amdgcn_mfma_f32_16x16x32_f16(A, Breg[2 * p], acc0, 0, 0, 0);
            acc1[0] = c1; acc1[1] = c1; acc1[2] = c1; acc1[3] = c1;
            acc1 = __builtin_amdgcn_mfma_f32_16x16x32_f16(A, Breg[2 * p + 1], acc1, 0, 0, 0);
            unsigned t0 = (unsigned)(wv * 8 + 2 * p), t1 = t0 + 1;
#pragma unroll
            for (int r = 0; r < 4; ++r) {
                unsigned k0 = (__float_as_uint(acc0[r]) & KMASK) | t0;
                unsigned k1 = (__float_as_uint(acc1[r]) & KMASK) | t1;
                unsigned med;
                asm("v_med3_u32 %0, %1, %2, %3"
                    : "=v"(med) : "v"(m1u[r]), "v"(k0), "v"(k1));
                asm("v_min3_u32 %0, %1, %2, %3"
                    : "=v"(m1u[r]) : "v"(m1u[r]), "v"(k0), "v"(k1));
                m2u[r] = umin_(m2u[r], med);
            }
        }

        // joint (min, 2nd-min) butterfly in packed-uint domain; idx via ballot.
        // key low 5 bits = t  =>  (score, t, g16) lexicographic == index order
        // => first-index tie-break preserved exactly.
#pragma unroll
        for (int r = 0; r < 4; ++r) {
            unsigned b1 = m1u[r], b2 = m2u[r];
#pragma unroll
            for (int dd = 1; dd <= 8; dd <<= 1) {
                unsigned o1 = __shfl_xor(b1, dd, 64);
                unsigned o2 = __shfl_xor(b2, dd, 64);
                b2 = umin_(umin_(b2, o2), umax_(b1, o1));
                b1 = umin_(b1, o1);
            }
            unsigned long long bal = __ballot(m1u[r] == b1) & grpmask;
            int wg16 = __builtin_ctzll(bal) - kg * 16;   // first-index tie-break
            int ai = (int)(b1 & 31u) * 16 + wg16;
            if (g16 == r)   // holder writes row tt*16 + 4*kg + r, slot wv
                pw[tt * 16 + 4 * kg + r][wv] =
                    make_float4(__uint_as_float(b1 & KMASK),
                                __uint_as_float(b2 & KMASK),
                                __int_as_float(ai), 0.f);
        }
    }
    __syncthreads();

    // ---- epilogue: merge 4 wave-partials per row (thread tid = row) ----
    float b1 = 1e30f, b2 = 1e30f; int bai = 0x7FFFFFFF;
#pragma unroll
    for (int w = 0; w < 4; ++w) {
        float4 p = pw[tid][w];
        float v1 = p.x, v2 = p.y; int ai = __float_as_int(p.z);
        float nb2 = fminf(fmaxf(b1, v1), fminf(b2, v2));
        bool take = (v1 < b1) || (v1 == b1 && ai < bai);
        bai = take ? ai : bai;
        b1 = fminf(b1, v1);
        b2 = nb2;
    }

    // loss: ||z-q||^2 = ||z||^2 + (m1 - 1)
    {
        double contrib = ((double)b1 - 1.0) + (double)zz_s[tid];
#pragma unroll
        for (int off = 32; off; off >>= 1) contrib += __shfl_down(contrib, off, 64);
        if (l == 0) wsum[wv] = contrib;
    }

    // idx (+1024 marks near-tie rows for the fixup pass); no atomics anywhere
    bool flag = (b2 - b1) <= MARGIN_TRIG;
    idxo[vblock + tid] = (float)(bai + (flag ? FLAG_OFS : 0));
    win_s[tid] = bai;
    __syncthreads();
    if (tid == 0) partials[blockIdx.x] = wsum[0] + wsum[1] + wsum[2] + wsum[3];

    // z_q: 256 threads x 8 iters cover 256 rows x 32 floats, fully contiguous
    {
        const float4* cb4 = (const float4*)cbf;
        float4* zq4 = (float4*)zq;
        const int c = tid & 7;
#pragma unroll
        for (int it = 0; it < 8; ++it) {
            int r = it * 32 + (tid >> 3);
            int win = win_s[r];
            float4 val = cb4[(size_t)win * 8 + c];
            zq4[(size_t)(vblock + r) * 8 + c] = val;
        }
    }
}

// cold path: scan idxo for flagged rows (>=1024), exact wave-parallel rescan.
// Also (block 0) final loss reduction.
__global__ __launch_bounds__(256, 2) void vq_fixup(
        const float* __restrict__ z, const float* __restrict__ cbf,
        const float* __restrict__ c32g,
        float* __restrict__ zq, float* __restrict__ idxo,
        const double* __restrict__ partials, float* __restrict__ loss_out) {
    if (blockIdx.x == 0) {                      // final loss reduction
        const int tid = threadIdx.x;
        double s = 0.0;
#pragma unroll
        for (int i = 0; i < NBLK / 256; ++i) s += partials[i * 256 + tid];
#pragma unroll
        for (int off = 32; off; off >>= 1) s += __shfl_down(s, off, 64);
        __shared__ double w4[4];
        if ((tid & 63) == 0) w4[tid >> 6] = s;
        __syncthreads();
        if (tid == 0)
            *loss_out = (float)(1.25 * (w4[0] + w4[1] + w4[2] + w4[3])
                                / (double)ZQ_ELEMS);
    }

    const int l = threadIdx.x & 63;
    const int wave = (blockIdx.x * blockDim.x + threadIdx.x) >> 6;
    const int nwaves = (gridDim.x * blockDim.x) >> 6;

    for (int ch = wave; ch < NVEC / 64; ch += nwaves) {
        int v0 = ch * 64;
        float fv = idxo[v0 + l];
        unsigned long long m = __ballot(fv >= (float)FLAG_OFS);
        while (m) {
            int b = __builtin_ctzll(m); m &= m - 1;
            int v = v0 + b;
            const float* zv = z + (size_t)v * D;    // uniform addr -> broadcast
            float4 zr[8];                           // hoist z once (32 regs)
#pragma unroll
            for (int q = 0; q < 8; ++q) zr[q] = *(const float4*)(zv + q * 4);
            double Ad = 0.0;
#pragma unroll
            for (int q = 0; q < 8; ++q) {
                Ad = fma((double)zr[q].x, (double)zr[q].x, Ad);
                Ad = fma((double)zr[q].y, (double)zr[q].y, Ad);
                Ad = fma((double)zr[q].z, (double)zr[q].z, Ad);
                Ad = fma((double)zr[q].w, (double)zr[q].w, Ad);
            }
            float Af = (float)Ad;
            float best = 1e30f; int bi = 0;
#pragma unroll 4
            for (int j = 0; j < 8; ++j) {
                int c = l * 8 + j;                  // lane-major => index-ordered
                const float* w = cbf + (size_t)c * D;
                double bd = 0.0;
#pragma unroll
                for (int q = 0; q < 8; ++q) {
                    float4 wq = *(const float4*)(w + q * 4);
                    bd = fma((double)zr[q].x, (double)wq.x, bd);
                    bd = fma((double)zr[q].y, (double)wq.y, bd);
                    bd = fma((double)zr[q].z, (double)wq.z, bd);
                    bd = fma((double)zr[q].w, (double)wq.w, bd);
                }
                float B32 = (float)bd;              // platonic dot
                float dq = __fadd_rn(__fsub_rn(Af, __fmul_rn(2.0f, B32)), c32g[c]);
                if (dq < best) { best = dq; bi = c; }
            }
#pragma unroll
            for (int dd = 1; dd < 64; dd <<= 1) {
                float ob = __shfl_xor(best, dd, 64);
                int obi = __shfl_xor(bi, dd, 64);
                bool take = (ob < best) || (ob == best && obi < bi);
                best = take ? ob : best; bi = take ? obi : bi;
            }
            if (l == 0) idxo[v] = (float)bi;        // clears the +1024 flag too
            if (l < 8) {                            // one full 128B line
                float4 val = ((const float4*)cbf)[(size_t)bi * 8 + l];
                ((float4*)zq)[(size_t)v * 8 + l] = val;
            }
        }
    }
}

extern "C" void kernel_launch(void* const* d_in, const int* in_sizes, int n_in,
                              void* d_out, int out_size, void* d_ws, size_t ws_size,
                              hipStream_t stream) {
    const float* z  = (const float*)d_in[0];
    const float* cb = (const float*)d_in[1];
    float* out  = (float*)d_out;
    float* zq   = out;
    float* idxo = out + ZQ_ELEMS;
    float* loss = out + ZQ_ELEMS + NVEC;
    float*  ww   = (float*)((char*)d_ws + 64);
    float*  ww1  = (float*)((char*)d_ws + WW1_OFF);
    half8*  bfrag = (half8*)((char*)d_ws + BFRAG_OFF);
    double* partials = (double*)((char*)d_ws + PART_OFF);

    vq_prep<<<8, 256, 0, stream>>>(cb, ww, ww1, bfrag);
    vq_main<<<NBLK, 256, 0, stream>>>(z, cb, bfrag, ww1, zq, idxo, partials);
    vq_fixup<<<2048, 256, 0, stream>>>(z, cb, ww, zq, idxo, partials, loss);
}

// Round 15
// 159.878 us; speedup vs baseline: 2.3835x; 2.2826x over previous
//
#include <hip/hip_runtime.h>

#define N_CODES 512
#define D 32
#define NVEC (8192 * 64)          // 524288 vectors
#define ZQ_ELEMS (NVEC * D)
#define NBLK (NVEC / 256)         // 2048 main blocks
#define MARGIN_TRIG 7e-5f
#define SA (-1.0f / 16.0f)        // B = SA*z   (power of 2, exact)
#define SB (32.0f)                // A = SB*w   -> A*B sums to -2 z.w
#define KMASK7 0xFFFFFF80u        // clear 7 low mantissa bits for (t,r) tag
#define FLAG_OFS 1024             // idx += 1024 marks "needs exact rescan"

typedef _Float16 half8 __attribute__((ext_vector_type(8)));
typedef float f32x4 __attribute__((ext_vector_type(4)));

// ws: @64 float ww[512] (fixup) | @2112 float ww1[512] | @4160 bfrag (32768)
//     | @36928 double partials[2048]
#define WW1_OFF 2112
#define BFRAG_OFF 4160
#define PART_OFF 36928
#define STAGE_F4 2176             // (2048 + 32768) / 16, staged from ws+2112

__device__ __forceinline__ unsigned umin_(unsigned a, unsigned b) { return a < b ? a : b; }
__device__ __forceinline__ unsigned umax_(unsigned a, unsigned b) { return a > b ? a : b; }

__global__ void vq_prep(const float* __restrict__ cb, float* __restrict__ ww,
                        float* __restrict__ ww1, half8* __restrict__ bfrag) {
    int gid = blockIdx.x * 256 + threadIdx.x;   // 8 x 256 = 2048
    if (gid >= 2048) return;
    int t = gid >> 6, l = gid & 63;
    int code = t * 16 + (l & 15), koff = (l >> 4) * 8;
    const float* w = cb + (size_t)code * D + koff;
    half8 h;
#pragma unroll
    for (int j = 0; j < 8; ++j) h[j] = (_Float16)(SB * w[j]);
    bfrag[t * 64 + l] = h;                      // MFMA A-operand lane order
    if (koff == 0) {                            // platonic ||w||^2 -> f32
        const float* wr = cb + (size_t)code * D;
        double s = 0.0;
#pragma unroll
        for (int d = 0; d < D; ++d) s = fma((double)wr[d], (double)wr[d], s);
        ww[code] = (float)s;                    // exact, for fixup formula
        ww1[code] = (float)(1.0 + s);           // C-init (+1 => scores positive)
    }
}

// Transposed MFMA: A = codes (LDS fragments), B = z (registers).
// D[row=code kg*4+r][col=vector g16]. Each lane min-reduces its 128 codes
// IN-LANE (med3/min3 on packed keys); only a 2-step cross-kg butterfly per
// 16 vectors. Wave owns 64 rows end-to-end (no cross-wave merge).
__global__ __launch_bounds__(256, 4) void vq_main(
        const float* __restrict__ z, const float* __restrict__ cbf,
        const float4* __restrict__ stage_src,   // ws+2112: ww1 | bfrag
        float* __restrict__ zq, float* __restrict__ idxo,
        double* __restrict__ partials) {
    __shared__ __align__(16) char smem[38912];
    __shared__ double wsum[4];
    const int tid = threadIdx.x;

    {   // stage ww1 + code fragments into LDS
        float4* s4 = (float4*)smem;
#pragma unroll
        for (int i = 0; i < 9; ++i) {
            int k = i * 256 + tid;
            if (k < STAGE_F4) s4[k] = stage_src[k];
        }
    }
    const float* lds_cin = (const float*)smem;           // 1+||w||^2 [512]
    const char* lds_bf = smem + 2048;                    // A fragments (32KB)
    float4* scratch = (float4*)(smem + 34816);           // [256] (m1,m2,idx,zz)

    const int l = tid & 63, wv = tid >> 6;
    const int g16 = l & 15, kg = l >> 4, koff = kg * 8;
    const int vblock = blockIdx.x * 256;                 // block owns 256 rows
    const int vwave = vblock + wv * 64;                  // wave owns 64 rows

    __syncthreads();   // staging visible

#pragma unroll 1
    for (int vt = 0; vt < 4; ++vt) {
        const float* zp = z + (size_t)(vwave + vt * 16 + g16) * D + koff;
        float4 a0 = *(const float4*)zp;
        float4 a1 = *(const float4*)(zp + 4);
        half8 Bz;
        Bz[0] = (_Float16)(a0.x * SA); Bz[1] = (_Float16)(a0.y * SA);
        Bz[2] = (_Float16)(a0.z * SA); Bz[3] = (_Float16)(a0.w * SA);
        Bz[4] = (_Float16)(a1.x * SA); Bz[5] = (_Float16)(a1.y * SA);
        Bz[6] = (_Float16)(a1.z * SA); Bz[7] = (_Float16)(a1.w * SA);
        float ss = 0.f;                                  // ||z||^2 partial (8 elems)
        ss = fmaf(a0.x, a0.x, ss); ss = fmaf(a0.y, a0.y, ss);
        ss = fmaf(a0.z, a0.z, ss); ss = fmaf(a0.w, a0.w, ss);
        ss = fmaf(a1.x, a1.x, ss); ss = fmaf(a1.y, a1.y, ss);
        ss = fmaf(a1.z, a1.z, ss); ss = fmaf(a1.w, a1.w, ss);

        unsigned m1u = 0xFFFFFFFFu, m2u = 0xFFFFFFFFu;

#pragma unroll 8
        for (int t = 0; t < 32; ++t) {
            half8 W = *(const half8*)(lds_bf + t * 1024 + l * 16);
            f32x4 cv = *(const f32x4*)(lds_cin + t * 16 + kg * 4);
            f32x4 acc = __builtin_amdgcn_mfma_f32_16x16x32_f16(W, Bz, cv, 0, 0, 0);
            unsigned tb = (unsigned)(t << 2);
            unsigned k0 = (__float_as_uint(acc[0]) & KMASK7) | tb;
            unsigned k1 = (__float_as_uint(acc[1]) & KMASK7) | (tb | 1u);
            unsigned k2 = (__float_as_uint(acc[2]) & KMASK7) | (tb | 2u);
            unsigned k3 = (__float_as_uint(acc[3]) & KMASK7) | (tb | 3u);
            unsigned med0, med1;
            asm("v_med3_u32 %0, %1, %2, %3"
                : "=v"(med0) : "v"(m1u), "v"(k0), "v"(k1));
            asm("v_min3_u32 %0, %1, %2, %3"
                : "=v"(m1u) : "v"(m1u), "v"(k0), "v"(k1));
            m2u = umin_(m2u, med0);
            asm("v_med3_u32 %0, %1, %2, %3"
                : "=v"(med1) : "v"(m1u), "v"(k2), "v"(k3));
            asm("v_min3_u32 %0, %1, %2, %3"
                : "=v"(m1u) : "v"(m1u), "v"(k2), "v"(k3));
            m2u = umin_(m2u, med1);
        }

        // cross-kg reduce (lanes +-16, +-32): b1, b2, ss
        unsigned mymin = m1u;
        unsigned b1 = m1u, b2 = m2u;
#pragma unroll
        for (int dd = 16; dd <= 32; dd <<= 1) {
            unsigned o1 = __shfl_xor(b1, dd, 64);
            unsigned o2 = __shfl_xor(b2, dd, 64);
            float os = __shfl_xor(ss, dd, 64);
            b2 = umin_(umin_(b2, o2), umax_(b1, o1));
            b1 = umin_(b1, o1);
            ss += os;
        }
        // winner kg via ballot over this vector's 4 lanes (lowest kg on tie)
        unsigned long long bal =
            __ballot(mymin == b1) & (0x0001000100010001ull << g16);
        int firstl = __builtin_ctzll(bal);
        int code = (int)((b1 >> 2) & 31u) * 16 + (firstl >> 4) * 4 + (int)(b1 & 3u);
        if (kg == 0)
            scratch[wv * 64 + vt * 16 + g16] =
                make_float4(__uint_as_float(b1 & KMASK7),
                            __uint_as_float(b2 & KMASK7),
                            __int_as_float(code), ss);
    }
    __syncthreads();

    // ---- epilogue (block scope; no atomics) ----
    float4 my = scratch[tid];                    // row tid of this block
    int bai = __float_as_int(my.z);

    // loss: ||z-q||^2 = ||z||^2 + (m1 - 1)
    {
        double contrib = ((double)my.x - 1.0) + (double)my.w;
#pragma unroll
        for (int off = 32; off; off >>= 1) contrib += __shfl_down(contrib, off, 64);
        if (l == 0) wsum[wv] = contrib;
    }
    __syncthreads();
    if (tid == 0) partials[blockIdx.x] = wsum[0] + wsum[1] + wsum[2] + wsum[3];

    // idx (+1024 marks near-tie rows for the fixup pass)
    bool flag = (my.y - my.x) <= MARGIN_TRIG;
    idxo[vblock + tid] = (float)(bai + (flag ? FLAG_OFS : 0));

    // z_q: 256 threads x 8 iters cover 256 rows x 32 floats, fully contiguous
    {
        const float4* cb4 = (const float4*)cbf;
        float4* zq4 = (float4*)zq;
        const int c = tid & 7;
#pragma unroll
        for (int it = 0; it < 8; ++it) {
            int r = it * 32 + (tid >> 3);
            int win = __float_as_int(scratch[r].z);
            float4 val = cb4[(size_t)win * 8 + c];
            zq4[(size_t)(vblock + r) * 8 + c] = val;
        }
    }
}

// cold path: scan idxo for flagged rows (>=1024), exact wave-parallel rescan.
// Block 0 also does the final loss reduction.
__global__ __launch_bounds__(256, 2) void vq_fixup(
        const float* __restrict__ z, const float* __restrict__ cbf,
        const float* __restrict__ c32g,
        float* __restrict__ zq, float* __restrict__ idxo,
        const double* __restrict__ partials, float* __restrict__ loss_out) {
    if (blockIdx.x == 0) {                      // final loss reduction
        const int tid = threadIdx.x;
        double s = 0.0;
#pragma unroll
        for (int i = 0; i < NBLK / 256; ++i) s += partials[i * 256 + tid];
#pragma unroll
        for (int off = 32; off; off >>= 1) s += __shfl_down(s, off, 64);
        __shared__ double w4[4];
        if ((tid & 63) == 0) w4[tid >> 6] = s;
        __syncthreads();
        if (tid == 0)
            *loss_out = (float)(1.25 * (w4[0] + w4[1] + w4[2] + w4[3])
                                / (double)ZQ_ELEMS);
    }

    const int l = threadIdx.x & 63;
    const int wave = (blockIdx.x * blockDim.x + threadIdx.x) >> 6;
    const int nwaves = (gridDim.x * blockDim.x) >> 6;

    for (int ch = wave; ch < NVEC / 64; ch += nwaves) {
        int v0 = ch * 64;
        float fv = idxo[v0 + l];
        unsigned long long m = __ballot(fv >= (float)FLAG_OFS);
        while (m) {
            int b = __builtin_ctzll(m); m &= m - 1;
            int v = v0 + b;
            const float* zv = z + (size_t)v * D;    // uniform addr -> broadcast
            float4 zr[8];                           // hoist z once (32 regs)
#pragma unroll
            for (int q = 0; q < 8; ++q) zr[q] = *(const float4*)(zv + q * 4);
            double Ad = 0.0;
#pragma unroll
            for (int q = 0; q < 8; ++q) {
                Ad = fma((double)zr[q].x, (double)zr[q].x, Ad);
                Ad = fma((double)zr[q].y, (double)zr[q].y, Ad);
                Ad = fma((double)zr[q].z, (double)zr[q].z, Ad);
                Ad = fma((double)zr[q].w, (double)zr[q].w, Ad);
            }
            float Af = (float)Ad;
            float best = 1e30f; int bi = 0;
#pragma unroll 4
            for (int j = 0; j < 8; ++j) {
                int c = l * 8 + j;                  // lane-major => index-ordered
                const float* w = cbf + (size_t)c * D;
                double bd = 0.0;
#pragma unroll
                for (int q = 0; q < 8; ++q) {
                    float4 wq = *(const float4*)(w + q * 4);
                    bd = fma((double)zr[q].x, (double)wq.x, bd);
                    bd = fma((double)zr[q].y, (double)wq.y, bd);
                    bd = fma((double)zr[q].z, (double)wq.z, bd);
                    bd = fma((double)zr[q].w, (double)wq.w, bd);
                }
                float B32 = (float)bd;              // platonic dot
                float dq = __fadd_rn(__fsub_rn(Af, __fmul_rn(2.0f, B32)), c32g[c]);
                if (dq < best) { best = dq; bi = c; }
            }
#pragma unroll
            for (int dd = 1; dd < 64; dd <<= 1) {
                float ob = __shfl_xor(best, dd, 64);
                int obi = __shfl_xor(bi, dd, 64);
                bool take = (ob < best) || (ob == best && obi < bi);
                best = take ? ob : best; bi = take ? obi : bi;
            }
            if (l == 0) idxo[v] = (float)bi;        // clears the +1024 flag too
            if (l < 8) {                            // one full 128B line
                float4 val = ((const float4*)cbf)[(size_t)bi * 8 + l];
                ((float4*)zq)[(size_t)v * 8 + l] = val;
            }
        }
    }
}

extern "C" void kernel_launch(void* const* d_in, const int* in_sizes, int n_in,
                              void* d_out, int out_size, void* d_ws, size_t ws_size,
                              hipStream_t stream) {
    const float* z  = (const float*)d_in[0];
    const float* cb = (const float*)d_in[1];
    float* out  = (float*)d_out;
    float* zq   = out;
    float* idxo = out + ZQ_ELEMS;
    float* loss = out + ZQ_ELEMS + NVEC;
    float*  ww   = (float*)((char*)d_ws + 64);
    float*  ww1  = (float*)((char*)d_ws + WW1_OFF);
    half8*  bfrag = (half8*)((char*)d_ws + BFRAG_OFF);
    const float4* stage_src = (const float4*)((char*)d_ws + WW1_OFF);
    double* partials = (double*)((char*)d_ws + PART_OFF);

    vq_prep<<<8, 256, 0, stream>>>(cb, ww, ww1, bfrag);
    vq_main<<<NBLK, 256, 0, stream>>>(z, cb, stage_src, zq, idxo, partials);
    vq_fixup<<<2048, 256, 0, stream>>>(z, cb, ww, zq, idxo, partials, loss);
}

// Round 16
// 124.624 us; speedup vs baseline: 3.0577x; 1.2829x over previous
//
#include <hip/hip_runtime.h>

#define N_CODES 512
#define D 32
#define NVEC (8192 * 64)          // 524288 vectors
#define ZQ_ELEMS (NVEC * D)
#define NBLK (NVEC / 256)         // 2048 main blocks
#define MARGIN_TRIG 7e-5f
#define SA (-1.0f / 16.0f)        // B = SA*z   (power of 2, exact)
#define SB (32.0f)                // A = SB*w   -> A*B sums to -2 z.w
#define KMASK7 0xFFFFFF80u        // clear 7 low mantissa bits for (t,r) tag

typedef _Float16 half8 __attribute__((ext_vector_type(8)));
typedef float f32x4 __attribute__((ext_vector_type(4)));

// ws: @8 uint flagcnt | @64 float ww[512] | @2112 float ww1[512]
//     | @4160 bfrag (32768) | @36928 float wT[32][512] (65536)
//     | @102464 double partials[2048] (16384) | @118848 int worklist[...]
#define WW1_OFF 2112
#define BFRAG_OFF 4160
#define WT_OFF 36928
#define PART_OFF 102464
#define WL_OFF 118848
#define STAGE_F4 2176             // (2048 + 32768) / 16, staged from ws+2112

__device__ __forceinline__ unsigned umin_(unsigned a, unsigned b) { return a < b ? a : b; }
__device__ __forceinline__ unsigned umax_(unsigned a, unsigned b) { return a > b ? a : b; }

__global__ void vq_prep(const float* __restrict__ cb, float* __restrict__ ww,
                        float* __restrict__ ww1, half8* __restrict__ bfrag,
                        float* __restrict__ wT, unsigned* __restrict__ flagcnt) {
    int gid = blockIdx.x * 256 + threadIdx.x;   // 8 x 256 = 2048
    if (gid == 0) *flagcnt = 0u;
    if (gid >= 2048) return;
    int t = gid >> 6, l = gid & 63;
    int code = t * 16 + (l & 15), koff = (l >> 4) * 8;
    const float* w = cb + (size_t)code * D + koff;
    half8 h;
#pragma unroll
    for (int j = 0; j < 8; ++j) h[j] = (_Float16)(SB * w[j]);
    bfrag[t * 64 + l] = h;                      // MFMA A-operand lane order
#pragma unroll
    for (int j = 0; j < 8; ++j)                 // transposed codebook wT[d][code]
        wT[(koff + j) * N_CODES + code] = w[j];
    if (koff == 0) {                            // platonic ||w||^2 -> f32
        const float* wr = cb + (size_t)code * D;
        double s = 0.0;
#pragma unroll
        for (int d = 0; d < D; ++d) s = fma((double)wr[d], (double)wr[d], s);
        ww[code] = (float)s;                    // exact, for fixup formula
        ww1[code] = (float)(1.0 + s);           // C-init (+1 => scores positive)
    }
}

// Transposed MFMA: A = codes (LDS fragments), B = z (registers).
// D[row=code kg*4+r][col=vector g16]. Each lane min-reduces its 128 codes
// IN-LANE (med3/min3 on packed keys); 2-step cross-kg butterfly per 16 vecs.
__global__ __launch_bounds__(256, 4) void vq_main(
        const float* __restrict__ z, const float* __restrict__ cbf,
        const float4* __restrict__ stage_src,   // ws+2112: ww1 | bfrag
        float* __restrict__ zq, float* __restrict__ idxo,
        double* __restrict__ partials, unsigned* __restrict__ flagcnt,
        int* __restrict__ worklist, int wl_cap) {
    __shared__ __align__(16) char smem[38912];
    __shared__ double wsum[4];
    const int tid = threadIdx.x;

    {   // stage ww1 + code fragments into LDS
        float4* s4 = (float4*)smem;
#pragma unroll
        for (int i = 0; i < 9; ++i) {
            int k = i * 256 + tid;
            if (k < STAGE_F4) s4[k] = stage_src[k];
        }
    }
    const float* lds_cin = (const float*)smem;           // 1+||w||^2 [512]
    const char* lds_bf = smem + 2048;                    // A fragments (32KB)
    float4* scratch = (float4*)(smem + 34816);           // [256] (m1,m2,idx,zz)

    const int l = tid & 63, wv = tid >> 6;
    const int g16 = l & 15, kg = l >> 4, koff = kg * 8;
    const int vblock = blockIdx.x * 256;                 // block owns 256 rows
    const int vwave = vblock + wv * 64;                  // wave owns 64 rows

    __syncthreads();   // staging visible

#pragma unroll 1
    for (int vt = 0; vt < 4; ++vt) {
        const float* zp = z + (size_t)(vwave + vt * 16 + g16) * D + koff;
        float4 a0 = *(const float4*)zp;
        float4 a1 = *(const float4*)(zp + 4);
        half8 Bz;
        Bz[0] = (_Float16)(a0.x * SA); Bz[1] = (_Float16)(a0.y * SA);
        Bz[2] = (_Float16)(a0.z * SA); Bz[3] = (_Float16)(a0.w * SA);
        Bz[4] = (_Float16)(a1.x * SA); Bz[5] = (_Float16)(a1.y * SA);
        Bz[6] = (_Float16)(a1.z * SA); Bz[7] = (_Float16)(a1.w * SA);
        float ss = 0.f;                                  // ||z||^2 partial (8 elems)
        ss = fmaf(a0.x, a0.x, ss); ss = fmaf(a0.y, a0.y, ss);
        ss = fmaf(a0.z, a0.z, ss); ss = fmaf(a0.w, a0.w, ss);
        ss = fmaf(a1.x, a1.x, ss); ss = fmaf(a1.y, a1.y, ss);
        ss = fmaf(a1.z, a1.z, ss); ss = fmaf(a1.w, a1.w, ss);

        unsigned m1u = 0xFFFFFFFFu, m2u = 0xFFFFFFFFu;

#pragma unroll 8
        for (int t = 0; t < 32; ++t) {
            half8 W = *(const half8*)(lds_bf + t * 1024 + l * 16);
            f32x4 cv = *(const f32x4*)(lds_cin + t * 16 + kg * 4);
            f32x4 acc = __builtin_amdgcn_mfma_f32_16x16x32_f16(W, Bz, cv, 0, 0, 0);
            unsigned tb = (unsigned)(t << 2);
            unsigned k0 = (__float_as_uint(acc[0]) & KMASK7) | tb;
            unsigned k1 = (__float_as_uint(acc[1]) & KMASK7) | (tb | 1u);
            unsigned k2 = (__float_as_uint(acc[2]) & KMASK7) | (tb | 2u);
            unsigned k3 = (__float_as_uint(acc[3]) & KMASK7) | (tb | 3u);
            unsigned med0, med1;
            asm("v_med3_u32 %0, %1, %2, %3"
                : "=v"(med0) : "v"(m1u), "v"(k0), "v"(k1));
            asm("v_min3_u32 %0, %1, %2, %3"
                : "=v"(m1u) : "v"(m1u), "v"(k0), "v"(k1));
            m2u = umin_(m2u, med0);
            asm("v_med3_u32 %0, %1, %2, %3"
                : "=v"(med1) : "v"(m1u), "v"(k2), "v"(k3));
            asm("v_min3_u32 %0, %1, %2, %3"
                : "=v"(m1u) : "v"(m1u), "v"(k2), "v"(k3));
            m2u = umin_(m2u, med1);
        }

        // cross-kg reduce (lanes +-16, +-32): b1, b2, ss
        unsigned mymin = m1u;
        unsigned b1 = m1u, b2 = m2u;
#pragma unroll
        for (int dd = 16; dd <= 32; dd <<= 1) {
            unsigned o1 = __shfl_xor(b1, dd, 64);
            unsigned o2 = __shfl_xor(b2, dd, 64);
            float os = __shfl_xor(ss, dd, 64);
            b2 = umin_(umin_(b2, o2), umax_(b1, o1));
            b1 = umin_(b1, o1);
            ss += os;
        }
        // winner kg via ballot over this vector's 4 lanes (lowest kg on tie)
        unsigned long long bal =
            __ballot(mymin == b1) & (0x0001000100010001ull << g16);
        int firstl = __builtin_ctzll(bal);
        int code = (int)((b1 >> 2) & 31u) * 16 + (firstl >> 4) * 4 + (int)(b1 & 3u);
        if (kg == 0)
            scratch[wv * 64 + vt * 16 + g16] =
                make_float4(__uint_as_float(b1 & KMASK7),
                            __uint_as_float(b2 & KMASK7),
                            __int_as_float(code), ss);
    }
    __syncthreads();

    // ---- epilogue (block scope) ----
    float4 my = scratch[tid];                    // row tid of this block
    int bai = __float_as_int(my.z);

    // near-tie rows -> dense worklist (one uint atomic per wave; ~0 cost, R11)
    {
        bool flag = (my.y - my.x) <= MARGIN_TRIG;
        unsigned long long mask = __ballot(flag);
        if (mask) {
            int base = 0;
            if (l == 0) base = (int)atomicAdd(flagcnt, (unsigned)__popcll(mask));
            base = __shfl(base, 0, 64);
            if (flag) {
                int pos = base + (int)__popcll(mask & ((1ull << l) - 1ull));
                if (pos < wl_cap) worklist[pos] = vblock + tid;
            }
        }
    }

    // loss: ||z-q||^2 = ||z||^2 + (m1 - 1)
    {
        double contrib = ((double)my.x - 1.0) + (double)my.w;
#pragma unroll
        for (int off = 32; off; off >>= 1) contrib += __shfl_down(contrib, off, 64);
        if (l == 0) wsum[wv] = contrib;
    }
    __syncthreads();
    if (tid == 0) partials[blockIdx.x] = wsum[0] + wsum[1] + wsum[2] + wsum[3];

    // indices: 1KB contiguous per block
    idxo[vblock + tid] = (float)bai;

    // z_q: 256 threads x 8 iters cover 256 rows x 32 floats, fully contiguous
    {
        const float4* cb4 = (const float4*)cbf;
        float4* zq4 = (float4*)zq;
        const int c = tid & 7;
#pragma unroll
        for (int it = 0; it < 8; ++it) {
            int r = it * 32 + (tid >> 3);
            int win = __float_as_int(scratch[r].z);
            float4 val = cb4[(size_t)win * 8 + c];
            zq4[(size_t)(vblock + r) * 8 + c] = val;
        }
    }
}

// cold path: worklist entries, one per wave-iteration, COALESCED transposed
// codebook (wT[d][code]: lane l owns codes l+64k -> consecutive-lane floats).
// Block 0 also does the final loss reduction.
__global__ __launch_bounds__(256, 2) void vq_fixup(
        const float* __restrict__ z, const float* __restrict__ cbf,
        const float* __restrict__ wT, const float* __restrict__ c32g,
        float* __restrict__ zq, float* __restrict__ idxo,
        const unsigned* __restrict__ flagcnt,
        const int* __restrict__ worklist, int wl_cap,
        const double* __restrict__ partials, float* __restrict__ loss_out) {
    if (blockIdx.x == 0) {                      // final loss reduction
        const int tid = threadIdx.x;
        double s = 0.0;
#pragma unroll
        for (int i = 0; i < NBLK / 256; ++i) s += partials[i * 256 + tid];
#pragma unroll
        for (int off = 32; off; off >>= 1) s += __shfl_down(s, off, 64);
        __shared__ double w4[4];
        if ((tid & 63) == 0) w4[tid >> 6] = s;
        __syncthreads();
        if (tid == 0)
            *loss_out = (float)(1.25 * (w4[0] + w4[1] + w4[2] + w4[3])
                                / (double)ZQ_ELEMS);
    }

    int cnt = (int)*flagcnt; if (cnt > wl_cap) cnt = wl_cap;
    const int l = threadIdx.x & 63;
    const int wave = (blockIdx.x * blockDim.x + threadIdx.x) >> 6;
    const int nwaves = (gridDim.x * blockDim.x) >> 6;

    for (int e = wave; e < cnt; e += nwaves) {
        int v = worklist[e];
        const float* zv = z + (size_t)v * D;        // uniform addr -> broadcast
        float zd[D];
#pragma unroll
        for (int q = 0; q < 8; ++q) {
            float4 t = *(const float4*)(zv + q * 4);
            zd[4 * q + 0] = t.x; zd[4 * q + 1] = t.y;
            zd[4 * q + 2] = t.z; zd[4 * q + 3] = t.w;
        }
        double Ad = 0.0;
#pragma unroll
        for (int d = 0; d < D; ++d) Ad = fma((double)zd[d], (double)zd[d], Ad);
        float Af = (float)Ad;

        // 8 codes per lane: c = l + 64k ; coalesced wT loads, 8 parallel chains
        double bd[8];
#pragma unroll
        for (int k = 0; k < 8; ++k) bd[k] = 0.0;
#pragma unroll 4
        for (int d = 0; d < D; ++d) {
            double zdd = (double)zd[d];
            const float* wrow = wT + (size_t)d * N_CODES + l;
#pragma unroll
            for (int k = 0; k < 8; ++k)
                bd[k] = fma(zdd, (double)wrow[64 * k], bd[k]);
        }
        float best = 1e30f; int bi = 0;
#pragma unroll
        for (int k = 0; k < 8; ++k) {
            int c = l + 64 * k;
            float B32 = (float)bd[k];               // platonic dot
            float dq = __fadd_rn(__fsub_rn(Af, __fmul_rn(2.0f, B32)), c32g[c]);
            if (dq < best) { best = dq; bi = c; }   // k asc => c asc: first-index
        }
#pragma unroll
        for (int dd = 1; dd < 64; dd <<= 1) {
            float ob = __shfl_xor(best, dd, 64);
            int obi = __shfl_xor(bi, dd, 64);
            bool take = (ob < best) || (ob == best && obi < bi);
            best = take ? ob : best; bi = take ? obi : bi;
        }
        if (l == 0) idxo[v] = (float)bi;
        if (l < 8) {                                // one full 128B line
            float4 val = ((const float4*)cbf)[(size_t)bi * 8 + l];
            ((float4*)zq)[(size_t)v * 8 + l] = val;
        }
    }
}

extern "C" void kernel_launch(void* const* d_in, const int* in_sizes, int n_in,
                              void* d_out, int out_size, void* d_ws, size_t ws_size,
                              hipStream_t stream) {
    const float* z  = (const float*)d_in[0];
    const float* cb = (const float*)d_in[1];
    float* out  = (float*)d_out;
    float* zq   = out;
    float* idxo = out + ZQ_ELEMS;
    float* loss = out + ZQ_ELEMS + NVEC;
    unsigned* flagcnt = (unsigned*)((char*)d_ws + 8);
    float*  ww   = (float*)((char*)d_ws + 64);
    float*  ww1  = (float*)((char*)d_ws + WW1_OFF);
    half8*  bfrag = (half8*)((char*)d_ws + BFRAG_OFF);
    float*  wT   = (float*)((char*)d_ws + WT_OFF);
    const float4* stage_src = (const float4*)((char*)d_ws + WW1_OFF);
    double* partials = (double*)((char*)d_ws + PART_OFF);
    int*    worklist = (int*)((char*)d_ws + WL_OFF);
    long long avail = (long long)ws_size - WL_OFF;
    int wl_cap = avail > 0 ? (int)(avail / 4 < NVEC ? avail / 4 : NVEC) : 0;

    vq_prep<<<8, 256, 0, stream>>>(cb, ww, ww1, bfrag, wT, flagcnt);
    vq_main<<<NBLK, 256, 0, stream>>>(z, cb, stage_src, zq, idxo,
                                      partials, flagcnt, worklist, wl_cap);
    vq_fixup<<<1024, 256, 0, stream>>>(z, cb, wT, ww, zq, idxo,
                                       flagcnt, worklist, wl_cap, partials, loss);
}